// Round 13
// baseline (323.332 us; speedup 1.0000x reference)
//
#include <hip/hip_runtime.h>
#include <math.h>

// Problem constants
#define T_SEQ 4096
#define CDIM  768
#define NH    12
#define HD    64
#define BATCH 2
#define MROWS (BATCH * T_SEQ)   // 8192
#define N3C   (3 * CDIM)        // 2304
#define HEADS_TOTAL (BATCH * NH)                       // 24
#define QKV_ELEMS   ((size_t)HEADS_TOTAL * T_SEQ * HD) // 6,291,456

// Q pre-scale: 1/sqrt(64) * log2(e)  (softmax in base 2)
#define QSCALE 0.18033688011112042f
// Fixed softmax shift, folded into the QK MFMA C-init: P = 2^(S-12).
// Validated R6 (absmax unchanged).
#define SSHIFT -12.0f

typedef __bf16 bf16x8 __attribute__((ext_vector_type(8)));
typedef __bf16 bf16x4 __attribute__((ext_vector_type(4)));
typedef __bf16 bf16x2 __attribute__((ext_vector_type(2)));
typedef float  f32x4  __attribute__((ext_vector_type(4)));
typedef short  s16x4  __attribute__((ext_vector_type(4)));

union b4u { bf16x4 h; s16x4 s; };
__device__ __forceinline__ s16x4 as_s16(bf16x4 v) { b4u u; u.h = v; return u.s; }

typedef __attribute__((address_space(1))) const void as1_cvoid;
typedef __attribute__((address_space(3))) void as3_void;

__device__ __forceinline__ void gl16(const void* g, void* l) {
  __builtin_amdgcn_global_load_lds((as1_cvoid*)g, (as3_void*)l, 16, 0, 0);
}

// ---------------------------------------------------------------------------
// R17-validated fused prep kernel — cast_x + both weight transpose-casts in
// ONE launch (block-uniform branch; bodies identical to the R4-validated
// kernels). Worth ~3.5-4us of launch gaps.
//   blocks [0, 3072)          : x fp32 -> bf16 (8 elems/thread)
//   blocks [3072, 3072+432)   : W_qkv transpose-cast (36 x 12 tiles)
//   blocks [3504, 3504+144)   : W_proj transpose-cast (12 x 12 tiles)
// ---------------------------------------------------------------------------
__device__ __forceinline__ void tcast_body(
    const float* __restrict__ W, __bf16* __restrict__ Wt, int K, int N,
    int bx, int by, float (*tile)[65]) {
  const int t  = threadIdx.x;
  const int k0 = by * 64, n0 = bx * 64;
  const int r  = t >> 4, c4 = (t & 15) << 2;
#pragma unroll
  for (int i = 0; i < 4; ++i) {
    float4 v = *(const float4*)&W[(size_t)(k0 + r + i * 16) * N + n0 + c4];
    tile[r + i * 16][c4 + 0] = v.x; tile[r + i * 16][c4 + 1] = v.y;
    tile[r + i * 16][c4 + 2] = v.z; tile[r + i * 16][c4 + 3] = v.w;
  }
  __syncthreads();
#pragma unroll
  for (int i = 0; i < 4; ++i) {
    int nr = r + i * 16;
    bf16x4 o;
    o[0] = (__bf16)tile[c4 + 0][nr]; o[1] = (__bf16)tile[c4 + 1][nr];
    o[2] = (__bf16)tile[c4 + 2][nr]; o[3] = (__bf16)tile[c4 + 3][nr];
    *(bf16x4*)&Wt[(size_t)(n0 + nr) * K + k0 + c4] = o;
  }
}

__global__ __launch_bounds__(256) void prep_kernel(
    const float* __restrict__ x, __bf16* __restrict__ xb,
    const float* __restrict__ Wq, __bf16* __restrict__ Wqt,
    const float* __restrict__ Wp, __bf16* __restrict__ Wpt) {
  __shared__ float tile[64][65];
  const int blk = (int)blockIdx.x;
  if (blk < 3072) {
    int i = (blk * 256 + (int)threadIdx.x) * 8;
    float4 a = *(const float4*)&x[i];
    float4 b = *(const float4*)&x[i + 4];
    bf16x8 o;
    o[0] = (__bf16)a.x; o[1] = (__bf16)a.y; o[2] = (__bf16)a.z; o[3] = (__bf16)a.w;
    o[4] = (__bf16)b.x; o[5] = (__bf16)b.y; o[6] = (__bf16)b.z; o[7] = (__bf16)b.w;
    *(bf16x8*)&xb[i] = o;
  } else if (blk < 3072 + 432) {
    const int idx = blk - 3072;
    tcast_body(Wq, Wqt, CDIM, N3C, idx % 36, idx / 36, tile);
  } else {
    const int idx = blk - 3504;
    tcast_body(Wp, Wpt, CDIM, CDIM, idx % 12, idx / 12, tile);
  }
}

// ---------------------------------------------------------------------------
// m97-style bf16 MFMA GEMM main loop (R4-validated).
// ---------------------------------------------------------------------------
__device__ __forceinline__ void mm_loop(const __bf16* __restrict__ A,
                                        const __bf16* __restrict__ Bt,
                                        int m0, int n0, __bf16* smem,
                                        f32x4 acc[4][4]) {
  const int t = threadIdx.x, wv = t >> 6, lane = t & 63;
  const int g2 = lane >> 4, c = lane & 15;
  __bf16* At = smem;
  __bf16* Bs = smem + 4096;
  const int ch0 = wv * 64 + lane;
  const int ch1 = 256 + ch0;
  const __bf16* gA0 = A  + (size_t)(m0 + (ch0 >> 2)) * CDIM + ((ch0 & 3) << 3);
  const __bf16* gA1 = A  + (size_t)(m0 + (ch1 >> 2)) * CDIM + ((ch1 & 3) << 3);
  const __bf16* gB0 = Bt + (size_t)(n0 + (ch0 >> 2)) * CDIM + ((ch0 & 3) << 3);
  const __bf16* gB1 = Bt + (size_t)(n0 + (ch1 >> 2)) * CDIM + ((ch1 & 3) << 3);
  __bf16* lA0 = At + (size_t)(wv * 64) * 8;
  __bf16* lA1 = At + (size_t)(256 + wv * 64) * 8;
  __bf16* lB0 = Bs + (size_t)(wv * 64) * 8;
  __bf16* lB1 = Bs + (size_t)(256 + wv * 64) * 8;
  const int mw = (wv & 1) << 6, nw = (wv >> 1) << 6;

  for (int kk = 0; kk < CDIM / 32; ++kk) {
    __syncthreads();
    gl16(gA0, lA0); gl16(gA1, lA1);
    gl16(gB0, lB0); gl16(gB1, lB1);
    gA0 += 32; gA1 += 32; gB0 += 32; gB1 += 32;
    __syncthreads();
    bf16x8 af[4], bfr[4];
#pragma unroll
    for (int mq = 0; mq < 4; ++mq)
      af[mq] = *(const bf16x8*)&At[(size_t)(mw + mq * 16 + c) * 32 + (g2 << 3)];
#pragma unroll
    for (int nq = 0; nq < 4; ++nq)
      bfr[nq] = *(const bf16x8*)&Bs[(size_t)(nw + nq * 16 + c) * 32 + (g2 << 3)];
#pragma unroll
    for (int mq = 0; mq < 4; ++mq)
#pragma unroll
      for (int nq = 0; nq < 4; ++nq)
        acc[mq][nq] = __builtin_amdgcn_mfma_f32_16x16x32_bf16(
            af[mq], bfr[nq], acc[mq][nq], 0, 0, 0);
  }
  __syncthreads();
}

// ---------------------------------------------------------------------------
// Kernel 1: qkv projection (bf16 MFMA) + re-tile epilogue.
// R16-validated XCD-chunked block swizzle (T1): w = (l%8)*(nwg/8) + l/8.
// R19: occupancy attack — the m97-structure mm_loop runs ~164 VGPR naturally
// (guide m98 dump) -> 3 blocks/CU, but the grid is 4.5/CU (1152 blocks).
//  1. __launch_bounds__(256, 5): cap VGPR at 102 (acc floor is 64) ->
//     5 waves/SIMD capacity.
//  2. Epilogue LDS stride 72 -> 64 with XOR swizzle (col ^= (row&7)<<3,
//     8-elem granular, same on write+read; reads are full-stripe b128 =
//     throughput-optimal under any permutation, writes <=2-way = free).
//     LDS 36864 -> 32768 B -> 5 blocks/CU -> ALL 1152 blocks co-resident,
//     tail eliminated.
// ---------------------------------------------------------------------------
__global__ __launch_bounds__(256, 5) void qkv_mm_kernel(
    const __bf16* __restrict__ xb, const __bf16* __restrict__ Wt,
    const float* __restrict__ bias, __bf16* __restrict__ Qw,
    __bf16* __restrict__ Kw, __bf16* __restrict__ Vtw) {
  __shared__ __align__(16) __bf16 smem[16384];   // 32 KB
  f32x4 acc[4][4];
#pragma unroll
  for (int i = 0; i < 4; ++i)
#pragma unroll
    for (int j = 0; j < 4; ++j) acc[i][j] = (f32x4){0.f, 0.f, 0.f, 0.f};

  const int nwg = (N3C / 128) * (MROWS / 128);   // 1152
  const int l   = (int)(blockIdx.x + gridDim.x * blockIdx.y);
  const int w   = (l & 7) * (nwg >> 3) + (l >> 3);
  const int m0  = (w / (N3C / 128)) * 128;
  const int n0  = (w % (N3C / 128)) * 128;
  mm_loop(xb, Wt, m0, n0, smem, acc);

  const int t = threadIdx.x, wv = t >> 6, lane = t & 63;
  const int g2 = lane >> 4, c = lane & 15;
  const int sel = n0 / CDIM;
  const int nn0 = n0 - sel * CDIM;
  const int h   = (nn0 >> 6) + (wv >> 1);
  const int mbase = m0 + ((wv & 1) << 6);
  const int b = mbase >> 12, tp0 = mbase & 4095;
  const int bh = b * NH + h;
  __bf16* Ep = smem + wv * 4096;   // 64 rows x 64 cols, XOR-swizzled
  float bcol[4];
#pragma unroll
  for (int nq = 0; nq < 4; ++nq)
    bcol[nq] = bias[n0 + ((wv >> 1) << 6) + nq * 16 + c];

  const int r8 = lane >> 3, c8 = (lane & 7) << 3;
  if (sel < 2) {
    const float scl = (sel == 0) ? QSCALE : 1.0f;
#pragma unroll
    for (int mq = 0; mq < 4; ++mq)
#pragma unroll
      for (int nq = 0; nq < 4; ++nq)
#pragma unroll
        for (int r = 0; r < 4; ++r) {
          const int row = mq * 16 + (g2 << 2) + r;
          const int col = nq * 16 + c;
          Ep[(row << 6) + (col ^ ((row & 7) << 3))] =
              (__bf16)((acc[mq][nq][r] + bcol[nq]) * scl);
        }
    asm volatile("s_waitcnt lgkmcnt(0)" ::: "memory");
    __bf16* dst = (sel == 0) ? Qw : Kw;
#pragma unroll
    for (int p = 0; p < 8; ++p) {
      int row = p * 8 + r8;               // row & 7 == r8
      bf16x8 v = *(const bf16x8*)&Ep[(row << 6) + (c8 ^ (r8 << 3))];
      *(bf16x8*)&dst[((size_t)bh * T_SEQ + tp0 + row) * HD + c8] = v;
    }
  } else {
#pragma unroll
    for (int mq = 0; mq < 4; ++mq)
#pragma unroll
      for (int nq = 0; nq < 4; ++nq)
#pragma unroll
        for (int r = 0; r < 4; ++r) {
          const int row = nq * 16 + c;
          const int col = mq * 16 + (g2 << 2) + r;
          Ep[(row << 6) + (col ^ ((row & 7) << 3))] =
              (__bf16)(acc[mq][nq][r] + bcol[nq]);
        }
    asm volatile("s_waitcnt lgkmcnt(0)" ::: "memory");
#pragma unroll
    for (int p = 0; p < 8; ++p) {
      int d = p * 8 + r8;                 // d & 7 == r8
      bf16x8 v = *(const bf16x8*)&Ep[(d << 6) + (c8 ^ (r8 << 3))];
      *(bf16x8*)&Vtw[((size_t)bh * HD + d) * T_SEQ + tp0 + c8] = v;
    }
  }
}

// ---------------------------------------------------------------------------
// Kernel 2: causal flash attention. R10 VERBATIM — the experimentally
// established local optimum (~103.2us here). Structural deviations refuted:
// R11 counted-vmcnt/triple-buf (+3.5), R12 ones-MFMA l (+1), R13 V-from-L2
// (+268), R14 128-thread sharing (+21.5), R15 K-from-L2 (+120),
// R17 setprio (+3). Keep: uniform sequential complement pairing
// (65 iters/block), double-buffered K+V gl16 staging w/ inverse-swizzled
// source, XOR-swizzled reads, fixed-shift base-2 softmax in the C-init,
// raw v_exp_f32, VALU l-accum + epilogue shuffles.
// ---------------------------------------------------------------------------
__device__ __forceinline__ void stage_tile(const __bf16* gk, const __bf16* gv,
                                           __bf16* ldsK, __bf16* ldsV) {
  gl16(gk,              ldsK);
  gl16(gk + 8 * HD,     ldsK + 8 * 64);
  gl16(gv,              ldsV);
  gl16(gv + 8 * T_SEQ,  ldsV + 8 * 64);
}

__device__ __forceinline__ void attn_tile(
    const __bf16* __restrict__ Qb, const __bf16* __restrict__ Kb,
    const __bf16* __restrict__ Vb, __bf16* __restrict__ O,
    int b, int hh, int qt, int wv, int lane, int g2, int c,
    __bf16 (*KT)[64][64], __bf16 (*VT)[64][64]) {
  const int qw = qt * 64 + wv * 16;   // wave owns 16 q rows

  // Q^T B-fragments (QK, K-dim = d): lane holds Q[qw+c][ds*32+8*g2..+7]
  bf16x8 qf0 = *(const bf16x8*)&Qb[(size_t)(qw + c) * HD +      (g2 << 3)];
  bf16x8 qf1 = *(const bf16x8*)&Qb[(size_t)(qw + c) * HD + 32 + (g2 << 3)];

  f32x4 ot[4];
#pragma unroll
  for (int dt = 0; dt < 4; ++dt) ot[dt] = (f32x4){0.f, 0.f, 0.f, 0.f};
  f32x4 lacc = (f32x4){0.f, 0.f, 0.f, 0.f};

  // per-lane global source for gl16 staging (inverse-swizzled column)
  const int rr = lane >> 3;
  const int lc = ((lane & 7) ^ rr) << 3;
  const __bf16* gk = Kb + (size_t)(wv * 16 + rr) * HD    + lc;
  const __bf16* gv = Vb + (size_t)(wv * 16 + rr) * T_SEQ + lc;

  stage_tile(gk, gv, &KT[0][wv * 16][0], &VT[0][wv * 16][0]);
  gk += 64 * HD; gv += 64;
  __syncthreads();

  const int swz  = (c & 7) << 3;
  const int qloc = (wv << 4) + c;
  const f32x4 SINIT = (f32x4){SSHIFT, SSHIFT, SSHIFT, SSHIFT};

#pragma unroll 1
  for (int kt = 0; kt <= qt; ++kt) {
    const int cur = kt & 1;
    if (kt < qt) {
      stage_tile(gk, gv, &KT[cur ^ 1][wv * 16][0], &VT[cur ^ 1][wv * 16][0]);
      gk += 64 * HD; gv += 64;
    }

    // S[s=64][q=16] = K . Q^T + SSHIFT (4 s-subtiles)
    f32x4 S[4];
#pragma unroll
    for (int st = 0; st < 4; ++st) {
      bf16x8 kfa = *(const bf16x8*)&KT[cur][st * 16 + c][(g2 << 3) ^ swz];
      bf16x8 kfb = *(const bf16x8*)&KT[cur][st * 16 + c][((4 + g2) << 3) ^ swz];
      S[st] = __builtin_amdgcn_mfma_f32_16x16x32_bf16(kfa, qf0, SINIT, 0, 0, 0);
      S[st] = __builtin_amdgcn_mfma_f32_16x16x32_bf16(kfb, qf1, S[st], 0, 0, 0);
    }

    if (kt == qt) {   // diagonal tile
#pragma unroll
      for (int st = 0; st < 4; ++st)
#pragma unroll
        for (int r = 0; r < 4; ++r)
          if ((st << 4) + (g2 << 2) + r > qloc) S[st][r] = -INFINITY;
    }

    // P = 2^S in-register (raw v_exp_f32)
    s16x4 pf[4];
#pragma unroll
    for (int st = 0; st < 4; ++st) {
      bf16x4 ph;
#pragma unroll
      for (int r = 0; r < 4; ++r) {
        float pl = __builtin_amdgcn_exp2f(S[st][r]);
        lacc[r] += pl;
        ph[r] = (__bf16)pl;
      }
      pf[st] = as_s16(ph);
    }

    // O += V^T . P : 4 dt x 4 st of 16x16x16
#pragma unroll
    for (int dt = 0; dt < 4; ++dt) {
#pragma unroll
      for (int st = 0; st < 4; ++st) {
        bf16x4 vh = *(const bf16x4*)&VT[cur][dt * 16 + c]
                                       [((st << 4) + (g2 << 2)) ^ swz];
        ot[dt] = __builtin_amdgcn_mfma_f32_16x16x16bf16_1k(as_s16(vh), pf[st],
                                                           ot[dt], 0, 0, 0);
      }
    }
    __syncthreads();
  }

  // ---- epilogue: finish l, normalize, write bf16 O ----
  float l = lacc[0] + lacc[1] + lacc[2] + lacc[3];
  l += __shfl_xor(l, 16);
  l += __shfl_xor(l, 32);
  const float inv = 1.f / l;
  __bf16* orow = O + ((size_t)(b * T_SEQ + qw + c)) * CDIM + hh * HD;
#pragma unroll
  for (int dt = 0; dt < 4; ++dt) {
    bf16x4 v;
    v[0] = (__bf16)(ot[dt][0] * inv); v[1] = (__bf16)(ot[dt][1] * inv);
    v[2] = (__bf16)(ot[dt][2] * inv); v[3] = (__bf16)(ot[dt][3] * inv);
    *(bf16x4*)&orow[dt * 16 + (g2 << 2)] = v;
  }
}

__global__ __launch_bounds__(256) void attn_kernel(
    const __bf16* __restrict__ Q, const __bf16* __restrict__ K,
    const __bf16* __restrict__ Vt, __bf16* __restrict__ O) {
  __shared__ __align__(16) __bf16 KT[2][64][64];   // 16 KB, XOR-swizzled
  __shared__ __align__(16) __bf16 VT[2][64][64];   // 16 KB, XOR-swizzled

  const int t    = threadIdx.x;
  const int wv   = t >> 6;
  const int lane = t & 63;
  const int g2   = lane >> 4;
  const int c    = lane & 15;
  const int bh   = blockIdx.x;              // XCD-local (24 ≡ 0 mod 8)
  const int p    = (int)blockIdx.y;         // 0..31

  const __bf16* Qb = Q  + (size_t)bh * T_SEQ * HD;
  const __bf16* Kb = K  + (size_t)bh * T_SEQ * HD;
  const __bf16* Vb = Vt + (size_t)bh * HD * T_SEQ;
  const int b = bh / NH, hh = bh % NH;

  // Phase A: q-tile p (k = 0..p). Phase B: q-tile 63-p (k = 0..63-p).
  // Total = 65 k-iterations for every block: exactly uniform cost.
  attn_tile(Qb, Kb, Vb, O, b, hh, p,      wv, lane, g2, c, KT, VT);
  attn_tile(Qb, Kb, Vb, O, b, hh, 63 - p, wv, lane, g2, c, KT, VT);
}

// ---------------------------------------------------------------------------
// Kernel 3: out = Ob @ Wprojt^T + b_proj (bf16 MFMA, fp32 out).
// R16-validated XCD-chunked swizzle (nwg = 384). Grid is 1.5 blocks/CU —
// already fully resident at natural VGPR, so no launch_bounds needed.
// ---------------------------------------------------------------------------
__global__ __launch_bounds__(256) void proj_mm_kernel(
    const __bf16* __restrict__ Ob, const __bf16* __restrict__ Wt,
    const float* __restrict__ bias, float* __restrict__ out) {
  __shared__ __align__(16) __bf16 smem[8192];
  f32x4 acc[4][4];
#pragma unroll
  for (int i = 0; i < 4; ++i)
#pragma unroll
    for (int j = 0; j < 4; ++j) acc[i][j] = (f32x4){0.f, 0.f, 0.f, 0.f};

  const int nwg = (CDIM / 128) * (MROWS / 128);   // 384
  const int l   = (int)(blockIdx.x + gridDim.x * blockIdx.y);
  const int w   = (l & 7) * (nwg >> 3) + (l >> 3);
  const int m0  = (w / (CDIM / 128)) * 128;
  const int n0  = (w % (CDIM / 128)) * 128;
  mm_loop(Ob, Wt, m0, n0, smem, acc);

  const int t = threadIdx.x, wv = t >> 6, lane = t & 63;
  const int g2 = lane >> 4, c = lane & 15;
  const int mb = m0 + ((wv & 1) << 6), nb = n0 + ((wv >> 1) << 6);
  float bcol[4];
#pragma unroll
  for (int nq = 0; nq < 4; ++nq) bcol[nq] = bias[nb + nq * 16 + c];
#pragma unroll
  for (int mq = 0; mq < 4; ++mq)
#pragma unroll
    for (int nq = 0; nq < 4; ++nq)
#pragma unroll
      for (int r = 0; r < 4; ++r)
        out[(size_t)(mb + mq * 16 + (g2 << 2) + r) * CDIM + nb + nq * 16 + c] =
            acc[mq][nq][r] + bcol[nq];
}

// ---------------------------------------------------------------------------
extern "C" void kernel_launch(void* const* d_in, const int* in_sizes, int n_in,
                              void* d_out, int out_size, void* d_ws, size_t ws_size,
                              hipStream_t stream) {
  (void)in_sizes; (void)n_in; (void)out_size; (void)ws_size;
  const float* x      = (const float*)d_in[0];
  const float* W_qkv  = (const float*)d_in[1];
  const float* b_qkv  = (const float*)d_in[2];
  const float* W_proj = (const float*)d_in[3];
  const float* b_proj = (const float*)d_in[4];
  float* out = (float*)d_out;

  __bf16* Qw     = (__bf16*)d_ws;
  __bf16* Kw     = Qw  + QKV_ELEMS;
  __bf16* Vtw    = Kw  + QKV_ELEMS;
  __bf16* Ob     = Vtw + QKV_ELEMS;
  __bf16* xb     = Ob  + QKV_ELEMS;
  __bf16* Wqkvt  = xb  + QKV_ELEMS;
  __bf16* Wprojt = Wqkvt + (size_t)CDIM * N3C;

  // Fused preps: 3072 cast blocks + 432 W_qkv tcast + 144 W_proj tcast
  prep_kernel<<<3072 + 432 + 144, 256, 0, stream>>>(
      x, xb, W_qkv, Wqkvt, W_proj, Wprojt);

  qkv_mm_kernel<<<dim3(N3C / 128, MROWS / 128), 256, 0, stream>>>(
      xb, Wqkvt, b_qkv, Qw, Kw, Vtw);

  attn_kernel<<<dim3(HEADS_TOTAL, 32), 256, 0, stream>>>(Qw, Kw, Vtw, Ob);

  proj_mm_kernel<<<dim3(CDIM / 128, MROWS / 128), 256, 0, stream>>>(
      Ob, Wprojt, b_proj, out);
}

// Round 14
// 289.291 us; speedup vs baseline: 1.1177x; 1.1177x over previous
//
#include <hip/hip_runtime.h>
#include <math.h>

// Problem constants
#define T_SEQ 4096
#define CDIM  768
#define NH    12
#define HD    64
#define BATCH 2
#define MROWS (BATCH * T_SEQ)   // 8192
#define N3C   (3 * CDIM)        // 2304
#define HEADS_TOTAL (BATCH * NH)                       // 24
#define QKV_ELEMS   ((size_t)HEADS_TOTAL * T_SEQ * HD) // 6,291,456

// Q pre-scale: 1/sqrt(64) * log2(e)  (softmax in base 2)
#define QSCALE 0.18033688011112042f
// Fixed softmax shift, folded into the QK MFMA C-init: P = 2^(S-12).
// Validated R6 (absmax unchanged).
#define SSHIFT -12.0f

typedef __bf16 bf16x8 __attribute__((ext_vector_type(8)));
typedef __bf16 bf16x4 __attribute__((ext_vector_type(4)));
typedef __bf16 bf16x2 __attribute__((ext_vector_type(2)));
typedef float  f32x4  __attribute__((ext_vector_type(4)));
typedef short  s16x4  __attribute__((ext_vector_type(4)));

union b4u { bf16x4 h; s16x4 s; };
__device__ __forceinline__ s16x4 as_s16(bf16x4 v) { b4u u; u.h = v; return u.s; }

typedef __attribute__((address_space(1))) const void as1_cvoid;
typedef __attribute__((address_space(3))) void as3_void;

__device__ __forceinline__ void gl16(const void* g, void* l) {
  __builtin_amdgcn_global_load_lds((as1_cvoid*)g, (as3_void*)l, 16, 0, 0);
}

// ---------------------------------------------------------------------------
// R17-validated fused prep kernel — cast_x + both weight transpose-casts in
// ONE launch (block-uniform branch; bodies identical to the R4-validated
// kernels). Worth ~3.5-4us of launch gaps.
//   blocks [0, 3072)          : x fp32 -> bf16 (8 elems/thread)
//   blocks [3072, 3072+432)   : W_qkv transpose-cast (36 x 12 tiles)
//   blocks [3504, 3504+144)   : W_proj transpose-cast (12 x 12 tiles)
// ---------------------------------------------------------------------------
__device__ __forceinline__ void tcast_body(
    const float* __restrict__ W, __bf16* __restrict__ Wt, int K, int N,
    int bx, int by, float (*tile)[65]) {
  const int t  = threadIdx.x;
  const int k0 = by * 64, n0 = bx * 64;
  const int r  = t >> 4, c4 = (t & 15) << 2;
#pragma unroll
  for (int i = 0; i < 4; ++i) {
    float4 v = *(const float4*)&W[(size_t)(k0 + r + i * 16) * N + n0 + c4];
    tile[r + i * 16][c4 + 0] = v.x; tile[r + i * 16][c4 + 1] = v.y;
    tile[r + i * 16][c4 + 2] = v.z; tile[r + i * 16][c4 + 3] = v.w;
  }
  __syncthreads();
#pragma unroll
  for (int i = 0; i < 4; ++i) {
    int nr = r + i * 16;
    bf16x4 o;
    o[0] = (__bf16)tile[c4 + 0][nr]; o[1] = (__bf16)tile[c4 + 1][nr];
    o[2] = (__bf16)tile[c4 + 2][nr]; o[3] = (__bf16)tile[c4 + 3][nr];
    *(bf16x4*)&Wt[(size_t)(n0 + nr) * K + k0 + c4] = o;
  }
}

__global__ __launch_bounds__(256) void prep_kernel(
    const float* __restrict__ x, __bf16* __restrict__ xb,
    const float* __restrict__ Wq, __bf16* __restrict__ Wqt,
    const float* __restrict__ Wp, __bf16* __restrict__ Wpt) {
  __shared__ float tile[64][65];
  const int blk = (int)blockIdx.x;
  if (blk < 3072) {
    int i = (blk * 256 + (int)threadIdx.x) * 8;
    float4 a = *(const float4*)&x[i];
    float4 b = *(const float4*)&x[i + 4];
    bf16x8 o;
    o[0] = (__bf16)a.x; o[1] = (__bf16)a.y; o[2] = (__bf16)a.z; o[3] = (__bf16)a.w;
    o[4] = (__bf16)b.x; o[5] = (__bf16)b.y; o[6] = (__bf16)b.z; o[7] = (__bf16)b.w;
    *(bf16x8*)&xb[i] = o;
  } else if (blk < 3072 + 432) {
    const int idx = blk - 3072;
    tcast_body(Wq, Wqt, CDIM, N3C, idx % 36, idx / 36, tile);
  } else {
    const int idx = blk - 3504;
    tcast_body(Wp, Wpt, CDIM, CDIM, idx % 12, idx / 12, tile);
  }
}

// ---------------------------------------------------------------------------
// m97-style bf16 MFMA GEMM main loop (R4-validated).
// ---------------------------------------------------------------------------
__device__ __forceinline__ void mm_loop(const __bf16* __restrict__ A,
                                        const __bf16* __restrict__ Bt,
                                        int m0, int n0, __bf16* smem,
                                        f32x4 acc[4][4]) {
  const int t = threadIdx.x, wv = t >> 6, lane = t & 63;
  const int g2 = lane >> 4, c = lane & 15;
  __bf16* At = smem;
  __bf16* Bs = smem + 4096;
  const int ch0 = wv * 64 + lane;
  const int ch1 = 256 + ch0;
  const __bf16* gA0 = A  + (size_t)(m0 + (ch0 >> 2)) * CDIM + ((ch0 & 3) << 3);
  const __bf16* gA1 = A  + (size_t)(m0 + (ch1 >> 2)) * CDIM + ((ch1 & 3) << 3);
  const __bf16* gB0 = Bt + (size_t)(n0 + (ch0 >> 2)) * CDIM + ((ch0 & 3) << 3);
  const __bf16* gB1 = Bt + (size_t)(n0 + (ch1 >> 2)) * CDIM + ((ch1 & 3) << 3);
  __bf16* lA0 = At + (size_t)(wv * 64) * 8;
  __bf16* lA1 = At + (size_t)(256 + wv * 64) * 8;
  __bf16* lB0 = Bs + (size_t)(wv * 64) * 8;
  __bf16* lB1 = Bs + (size_t)(256 + wv * 64) * 8;
  const int mw = (wv & 1) << 6, nw = (wv >> 1) << 6;

  for (int kk = 0; kk < CDIM / 32; ++kk) {
    __syncthreads();
    gl16(gA0, lA0); gl16(gA1, lA1);
    gl16(gB0, lB0); gl16(gB1, lB1);
    gA0 += 32; gA1 += 32; gB0 += 32; gB1 += 32;
    __syncthreads();
    bf16x8 af[4], bfr[4];
#pragma unroll
    for (int mq = 0; mq < 4; ++mq)
      af[mq] = *(const bf16x8*)&At[(size_t)(mw + mq * 16 + c) * 32 + (g2 << 3)];
#pragma unroll
    for (int nq = 0; nq < 4; ++nq)
      bfr[nq] = *(const bf16x8*)&Bs[(size_t)(nw + nq * 16 + c) * 32 + (g2 << 3)];
#pragma unroll
    for (int mq = 0; mq < 4; ++mq)
#pragma unroll
      for (int nq = 0; nq < 4; ++nq)
        acc[mq][nq] = __builtin_amdgcn_mfma_f32_16x16x32_bf16(
            af[mq], bfr[nq], acc[mq][nq], 0, 0, 0);
  }
  __syncthreads();
}

// ---------------------------------------------------------------------------
// Kernel 1: qkv projection (bf16 MFMA) + re-tile epilogue.
// R20: R19's launch_bounds cap REVERTED (it spilled the unified-file
// accumulator: VGPR_Count 48 < the 64-reg acc floor, 280MB scratch WRITE,
// MfmaUtil 8.5%). Natural regs restored. Occupancy fixed the R10 way
// instead: PERSISTENT PAIRING — grid 576 blocks, each does 2 adjacent
// tiles (w = 2s, 2s+1; 2s is even so both share the same m-row -> the
// second tile's A-panel is L2-warm). Every block = identical cost, tail
// drops from ~half-grid to <=64 blocks. XCD chunking on the pair index
// (576 % 8 == 0). Keeps the R19-validated 32KB XOR-swizzled epilogue.
// ---------------------------------------------------------------------------
__global__ __launch_bounds__(256) void qkv_mm_kernel(
    const __bf16* __restrict__ xb, const __bf16* __restrict__ Wt,
    const float* __restrict__ bias, __bf16* __restrict__ Qw,
    __bf16* __restrict__ Kw, __bf16* __restrict__ Vtw) {
  __shared__ __align__(16) __bf16 smem[16384];   // 32 KB
  const int t = threadIdx.x, wv = t >> 6, lane = t & 63;
  const int g2 = lane >> 4, c = lane & 15;
  const int r8 = lane >> 3, c8 = (lane & 7) << 3;

  const int l = (int)blockIdx.x;                 // 0..575
  const int s = (l & 7) * 72 + (l >> 3);         // XCD-chunked pair index

#pragma unroll 1
  for (int half = 0; half < 2; ++half) {
    const int w  = 2 * s + half;
    const int m0 = (w / (N3C / 128)) * 128;
    const int n0 = (w % (N3C / 128)) * 128;

    f32x4 acc[4][4];
#pragma unroll
    for (int i = 0; i < 4; ++i)
#pragma unroll
      for (int j = 0; j < 4; ++j) acc[i][j] = (f32x4){0.f, 0.f, 0.f, 0.f};

    mm_loop(xb, Wt, m0, n0, smem, acc);

    const int sel = n0 / CDIM;
    const int nn0 = n0 - sel * CDIM;
    const int h   = (nn0 >> 6) + (wv >> 1);
    const int mbase = m0 + ((wv & 1) << 6);
    const int b = mbase >> 12, tp0 = mbase & 4095;
    const int bh = b * NH + h;
    __bf16* Ep = smem + wv * 4096;   // 64 rows x 64 cols, XOR-swizzled
    float bcol[4];
#pragma unroll
    for (int nq = 0; nq < 4; ++nq)
      bcol[nq] = bias[n0 + ((wv >> 1) << 6) + nq * 16 + c];

    if (sel < 2) {
      const float scl = (sel == 0) ? QSCALE : 1.0f;
#pragma unroll
      for (int mq = 0; mq < 4; ++mq)
#pragma unroll
        for (int nq = 0; nq < 4; ++nq)
#pragma unroll
          for (int r = 0; r < 4; ++r) {
            const int row = mq * 16 + (g2 << 2) + r;
            const int col = nq * 16 + c;
            Ep[(row << 6) + (col ^ ((row & 7) << 3))] =
                (__bf16)((acc[mq][nq][r] + bcol[nq]) * scl);
          }
      asm volatile("s_waitcnt lgkmcnt(0)" ::: "memory");
      __bf16* dst = (sel == 0) ? Qw : Kw;
#pragma unroll
      for (int p = 0; p < 8; ++p) {
        int row = p * 8 + r8;               // row & 7 == r8
        bf16x8 v = *(const bf16x8*)&Ep[(row << 6) + (c8 ^ (r8 << 3))];
        *(bf16x8*)&dst[((size_t)bh * T_SEQ + tp0 + row) * HD + c8] = v;
      }
    } else {
#pragma unroll
      for (int mq = 0; mq < 4; ++mq)
#pragma unroll
        for (int nq = 0; nq < 4; ++nq)
#pragma unroll
          for (int r = 0; r < 4; ++r) {
            const int row = nq * 16 + c;
            const int col = mq * 16 + (g2 << 2) + r;
            Ep[(row << 6) + (col ^ ((row & 7) << 3))] =
                (__bf16)(acc[mq][nq][r] + bcol[nq]);
          }
      asm volatile("s_waitcnt lgkmcnt(0)" ::: "memory");
#pragma unroll
      for (int p = 0; p < 8; ++p) {
        int d = p * 8 + r8;                 // d & 7 == r8
        bf16x8 v = *(const bf16x8*)&Ep[(d << 6) + (c8 ^ (r8 << 3))];
        *(bf16x8*)&Vtw[((size_t)bh * HD + d) * T_SEQ + tp0 + c8] = v;
      }
    }
  }
}

// ---------------------------------------------------------------------------
// Kernel 2: causal flash attention. R10 VERBATIM — the experimentally
// established local optimum (~103.2us). Structural deviations refuted:
// R11 counted-vmcnt/triple-buf (+3.5), R12 ones-MFMA l (+1), R13 V-from-L2
// (+268), R14 128-thread sharing (+21.5), R15 K-from-L2 (+120),
// R17 setprio (+3). Keep: uniform sequential complement pairing
// (65 iters/block), double-buffered K+V gl16 staging w/ inverse-swizzled
// source, XOR-swizzled reads, fixed-shift base-2 softmax in the C-init,
// raw v_exp_f32, VALU l-accum + epilogue shuffles.
// ---------------------------------------------------------------------------
__device__ __forceinline__ void stage_tile(const __bf16* gk, const __bf16* gv,
                                           __bf16* ldsK, __bf16* ldsV) {
  gl16(gk,              ldsK);
  gl16(gk + 8 * HD,     ldsK + 8 * 64);
  gl16(gv,              ldsV);
  gl16(gv + 8 * T_SEQ,  ldsV + 8 * 64);
}

__device__ __forceinline__ void attn_tile(
    const __bf16* __restrict__ Qb, const __bf16* __restrict__ Kb,
    const __bf16* __restrict__ Vb, __bf16* __restrict__ O,
    int b, int hh, int qt, int wv, int lane, int g2, int c,
    __bf16 (*KT)[64][64], __bf16 (*VT)[64][64]) {
  const int qw = qt * 64 + wv * 16;   // wave owns 16 q rows

  // Q^T B-fragments (QK, K-dim = d): lane holds Q[qw+c][ds*32+8*g2..+7]
  bf16x8 qf0 = *(const bf16x8*)&Qb[(size_t)(qw + c) * HD +      (g2 << 3)];
  bf16x8 qf1 = *(const bf16x8*)&Qb[(size_t)(qw + c) * HD + 32 + (g2 << 3)];

  f32x4 ot[4];
#pragma unroll
  for (int dt = 0; dt < 4; ++dt) ot[dt] = (f32x4){0.f, 0.f, 0.f, 0.f};
  f32x4 lacc = (f32x4){0.f, 0.f, 0.f, 0.f};

  // per-lane global source for gl16 staging (inverse-swizzled column)
  const int rr = lane >> 3;
  const int lc = ((lane & 7) ^ rr) << 3;
  const __bf16* gk = Kb + (size_t)(wv * 16 + rr) * HD    + lc;
  const __bf16* gv = Vb + (size_t)(wv * 16 + rr) * T_SEQ + lc;

  stage_tile(gk, gv, &KT[0][wv * 16][0], &VT[0][wv * 16][0]);
  gk += 64 * HD; gv += 64;
  __syncthreads();

  const int swz  = (c & 7) << 3;
  const int qloc = (wv << 4) + c;
  const f32x4 SINIT = (f32x4){SSHIFT, SSHIFT, SSHIFT, SSHIFT};

#pragma unroll 1
  for (int kt = 0; kt <= qt; ++kt) {
    const int cur = kt & 1;
    if (kt < qt) {
      stage_tile(gk, gv, &KT[cur ^ 1][wv * 16][0], &VT[cur ^ 1][wv * 16][0]);
      gk += 64 * HD; gv += 64;
    }

    // S[s=64][q=16] = K . Q^T + SSHIFT (4 s-subtiles)
    f32x4 S[4];
#pragma unroll
    for (int st = 0; st < 4; ++st) {
      bf16x8 kfa = *(const bf16x8*)&KT[cur][st * 16 + c][(g2 << 3) ^ swz];
      bf16x8 kfb = *(const bf16x8*)&KT[cur][st * 16 + c][((4 + g2) << 3) ^ swz];
      S[st] = __builtin_amdgcn_mfma_f32_16x16x32_bf16(kfa, qf0, SINIT, 0, 0, 0);
      S[st] = __builtin_amdgcn_mfma_f32_16x16x32_bf16(kfb, qf1, S[st], 0, 0, 0);
    }

    if (kt == qt) {   // diagonal tile
#pragma unroll
      for (int st = 0; st < 4; ++st)
#pragma unroll
        for (int r = 0; r < 4; ++r)
          if ((st << 4) + (g2 << 2) + r > qloc) S[st][r] = -INFINITY;
    }

    // P = 2^S in-register (raw v_exp_f32)
    s16x4 pf[4];
#pragma unroll
    for (int st = 0; st < 4; ++st) {
      bf16x4 ph;
#pragma unroll
      for (int r = 0; r < 4; ++r) {
        float pl = __builtin_amdgcn_exp2f(S[st][r]);
        lacc[r] += pl;
        ph[r] = (__bf16)pl;
      }
      pf[st] = as_s16(ph);
    }

    // O += V^T . P : 4 dt x 4 st of 16x16x16
#pragma unroll
    for (int dt = 0; dt < 4; ++dt) {
#pragma unroll
      for (int st = 0; st < 4; ++st) {
        bf16x4 vh = *(const bf16x4*)&VT[cur][dt * 16 + c]
                                       [((st << 4) + (g2 << 2)) ^ swz];
        ot[dt] = __builtin_amdgcn_mfma_f32_16x16x16bf16_1k(as_s16(vh), pf[st],
                                                           ot[dt], 0, 0, 0);
      }
    }
    __syncthreads();
  }

  // ---- epilogue: finish l, normalize, write bf16 O ----
  float l = lacc[0] + lacc[1] + lacc[2] + lacc[3];
  l += __shfl_xor(l, 16);
  l += __shfl_xor(l, 32);
  const float inv = 1.f / l;
  __bf16* orow = O + ((size_t)(b * T_SEQ + qw + c)) * CDIM + hh * HD;
#pragma unroll
  for (int dt = 0; dt < 4; ++dt) {
    bf16x4 v;
    v[0] = (__bf16)(ot[dt][0] * inv); v[1] = (__bf16)(ot[dt][1] * inv);
    v[2] = (__bf16)(ot[dt][2] * inv); v[3] = (__bf16)(ot[dt][3] * inv);
    *(bf16x4*)&orow[dt * 16 + (g2 << 2)] = v;
  }
}

__global__ __launch_bounds__(256) void attn_kernel(
    const __bf16* __restrict__ Q, const __bf16* __restrict__ K,
    const __bf16* __restrict__ Vt, __bf16* __restrict__ O) {
  __shared__ __align__(16) __bf16 KT[2][64][64];   // 16 KB, XOR-swizzled
  __shared__ __align__(16) __bf16 VT[2][64][64];   // 16 KB, XOR-swizzled

  const int t    = threadIdx.x;
  const int wv   = t >> 6;
  const int lane = t & 63;
  const int g2   = lane >> 4;
  const int c    = lane & 15;
  const int bh   = blockIdx.x;              // XCD-local (24 ≡ 0 mod 8)
  const int p    = (int)blockIdx.y;         // 0..31

  const __bf16* Qb = Q  + (size_t)bh * T_SEQ * HD;
  const __bf16* Kb = K  + (size_t)bh * T_SEQ * HD;
  const __bf16* Vb = Vt + (size_t)bh * HD * T_SEQ;
  const int b = bh / NH, hh = bh % NH;

  // Phase A: q-tile p (k = 0..p). Phase B: q-tile 63-p (k = 0..63-p).
  // Total = 65 k-iterations for every block: exactly uniform cost.
  attn_tile(Qb, Kb, Vb, O, b, hh, p,      wv, lane, g2, c, KT, VT);
  attn_tile(Qb, Kb, Vb, O, b, hh, 63 - p, wv, lane, g2, c, KT, VT);
}

// ---------------------------------------------------------------------------
// Kernel 3: out = Ob @ Wprojt^T + b_proj (bf16 MFMA, fp32 out).
// R16-validated XCD-chunked swizzle (nwg = 384). Grid is 1.5 blocks/CU —
// already fully resident at natural VGPR, so no launch_bounds needed.
// ---------------------------------------------------------------------------
__global__ __launch_bounds__(256) void proj_mm_kernel(
    const __bf16* __restrict__ Ob, const __bf16* __restrict__ Wt,
    const float* __restrict__ bias, float* __restrict__ out) {
  __shared__ __align__(16) __bf16 smem[8192];
  f32x4 acc[4][4];
#pragma unroll
  for (int i = 0; i < 4; ++i)
#pragma unroll
    for (int j = 0; j < 4; ++j) acc[i][j] = (f32x4){0.f, 0.f, 0.f, 0.f};

  const int nwg = (CDIM / 128) * (MROWS / 128);   // 384
  const int l   = (int)(blockIdx.x + gridDim.x * blockIdx.y);
  const int w   = (l & 7) * (nwg >> 3) + (l >> 3);
  const int m0  = (w / (CDIM / 128)) * 128;
  const int n0  = (w % (CDIM / 128)) * 128;
  mm_loop(Ob, Wt, m0, n0, smem, acc);

  const int t = threadIdx.x, wv = t >> 6, lane = t & 63;
  const int g2 = lane >> 4, c = lane & 15;
  const int mb = m0 + ((wv & 1) << 6), nb = n0 + ((wv >> 1) << 6);
  float bcol[4];
#pragma unroll
  for (int nq = 0; nq < 4; ++nq) bcol[nq] = bias[nb + nq * 16 + c];
#pragma unroll
  for (int mq = 0; mq < 4; ++mq)
#pragma unroll
    for (int nq = 0; nq < 4; ++nq)
#pragma unroll
      for (int r = 0; r < 4; ++r)
        out[(size_t)(mb + mq * 16 + (g2 << 2) + r) * CDIM + nb + nq * 16 + c] =
            acc[mq][nq][r] + bcol[nq];
}

// ---------------------------------------------------------------------------
extern "C" void kernel_launch(void* const* d_in, const int* in_sizes, int n_in,
                              void* d_out, int out_size, void* d_ws, size_t ws_size,
                              hipStream_t stream) {
  (void)in_sizes; (void)n_in; (void)out_size; (void)ws_size;
  const float* x      = (const float*)d_in[0];
  const float* W_qkv  = (const float*)d_in[1];
  const float* b_qkv  = (const float*)d_in[2];
  const float* W_proj = (const float*)d_in[3];
  const float* b_proj = (const float*)d_in[4];
  float* out = (float*)d_out;

  __bf16* Qw     = (__bf16*)d_ws;
  __bf16* Kw     = Qw  + QKV_ELEMS;
  __bf16* Vtw    = Kw  + QKV_ELEMS;
  __bf16* Ob     = Vtw + QKV_ELEMS;
  __bf16* xb     = Ob  + QKV_ELEMS;
  __bf16* Wqkvt  = xb  + QKV_ELEMS;
  __bf16* Wprojt = Wqkvt + (size_t)CDIM * N3C;

  // Fused preps: 3072 cast blocks + 432 W_qkv tcast + 144 W_proj tcast
  prep_kernel<<<3072 + 432 + 144, 256, 0, stream>>>(
      x, xb, W_qkv, Wqkvt, W_proj, Wprojt);

  // 576 persistent blocks, 2 same-row tiles each (uniform cost, no tail)
  qkv_mm_kernel<<<576, 256, 0, stream>>>(
      xb, Wqkvt, b_qkv, Qw, Kw, Vtw);

  attn_kernel<<<dim3(HEADS_TOTAL, 32), 256, 0, stream>>>(Qw, Kw, Vtw, Ob);

  proj_mm_kernel<<<dim3(CDIM / 128, MROWS / 128), 256, 0, stream>>>(
      Ob, Wprojt, b_proj, out);
}

// Round 15
// 236.034 us; speedup vs baseline: 1.3699x; 1.2256x over previous
//
#include <hip/hip_runtime.h>
#include <math.h>

// Problem constants
#define T_SEQ 4096
#define CDIM  768
#define NH    12
#define HD    64
#define BATCH 2
#define MROWS (BATCH * T_SEQ)   // 8192
#define N3C   (3 * CDIM)        // 2304
#define HEADS_TOTAL (BATCH * NH)                       // 24
#define QKV_ELEMS   ((size_t)HEADS_TOTAL * T_SEQ * HD) // 6,291,456

// Q pre-scale: 1/sqrt(64) * log2(e)  (softmax in base 2)
#define QSCALE 0.18033688011112042f
// Fixed softmax shift, folded into the QK MFMA C-init: P = 2^(S-12).
// Validated R6 (absmax unchanged).
#define SSHIFT -12.0f

typedef __bf16 bf16x8 __attribute__((ext_vector_type(8)));
typedef __bf16 bf16x4 __attribute__((ext_vector_type(4)));
typedef __bf16 bf16x2 __attribute__((ext_vector_type(2)));
typedef float  f32x4  __attribute__((ext_vector_type(4)));
typedef short  s16x4  __attribute__((ext_vector_type(4)));

union b4u { bf16x4 h; s16x4 s; };
__device__ __forceinline__ s16x4 as_s16(bf16x4 v) { b4u u; u.h = v; return u.s; }

typedef __attribute__((address_space(1))) const void as1_cvoid;
typedef __attribute__((address_space(3))) void as3_void;

__device__ __forceinline__ void gl16(const void* g, void* l) {
  __builtin_amdgcn_global_load_lds((as1_cvoid*)g, (as3_void*)l, 16, 0, 0);
}

// ---------------------------------------------------------------------------
// R17-validated fused prep kernel — cast_x + both weight transpose-casts in
// ONE launch (block-uniform branch; bodies identical to the R4-validated
// kernels). Worth ~3.5-4us of launch gaps.
//   blocks [0, 3072)          : x fp32 -> bf16 (8 elems/thread)
//   blocks [3072, 3072+432)   : W_qkv transpose-cast (36 x 12 tiles)
//   blocks [3504, 3504+144)   : W_proj transpose-cast (12 x 12 tiles)
// ---------------------------------------------------------------------------
__device__ __forceinline__ void tcast_body(
    const float* __restrict__ W, __bf16* __restrict__ Wt, int K, int N,
    int bx, int by, float (*tile)[65]) {
  const int t  = threadIdx.x;
  const int k0 = by * 64, n0 = bx * 64;
  const int r  = t >> 4, c4 = (t & 15) << 2;
#pragma unroll
  for (int i = 0; i < 4; ++i) {
    float4 v = *(const float4*)&W[(size_t)(k0 + r + i * 16) * N + n0 + c4];
    tile[r + i * 16][c4 + 0] = v.x; tile[r + i * 16][c4 + 1] = v.y;
    tile[r + i * 16][c4 + 2] = v.z; tile[r + i * 16][c4 + 3] = v.w;
  }
  __syncthreads();
#pragma unroll
  for (int i = 0; i < 4; ++i) {
    int nr = r + i * 16;
    bf16x4 o;
    o[0] = (__bf16)tile[c4 + 0][nr]; o[1] = (__bf16)tile[c4 + 1][nr];
    o[2] = (__bf16)tile[c4 + 2][nr]; o[3] = (__bf16)tile[c4 + 3][nr];
    *(bf16x4*)&Wt[(size_t)(n0 + nr) * K + k0 + c4] = o;
  }
}

__global__ __launch_bounds__(256) void prep_kernel(
    const float* __restrict__ x, __bf16* __restrict__ xb,
    const float* __restrict__ Wq, __bf16* __restrict__ Wqt,
    const float* __restrict__ Wp, __bf16* __restrict__ Wpt) {
  __shared__ float tile[64][65];
  const int blk = (int)blockIdx.x;
  if (blk < 3072) {
    int i = (blk * 256 + (int)threadIdx.x) * 8;
    float4 a = *(const float4*)&x[i];
    float4 b = *(const float4*)&x[i + 4];
    bf16x8 o;
    o[0] = (__bf16)a.x; o[1] = (__bf16)a.y; o[2] = (__bf16)a.z; o[3] = (__bf16)a.w;
    o[4] = (__bf16)b.x; o[5] = (__bf16)b.y; o[6] = (__bf16)b.z; o[7] = (__bf16)b.w;
    *(bf16x8*)&xb[i] = o;
  } else if (blk < 3072 + 432) {
    const int idx = blk - 3072;
    tcast_body(Wq, Wqt, CDIM, N3C, idx % 36, idx / 36, tile);
  } else {
    const int idx = blk - 3504;
    tcast_body(Wp, Wpt, CDIM, CDIM, idx % 12, idx / 12, tile);
  }
}

// ---------------------------------------------------------------------------
// m97-style bf16 MFMA GEMM main loop (R4-validated).
// ---------------------------------------------------------------------------
__device__ __forceinline__ void mm_loop(const __bf16* __restrict__ A,
                                        const __bf16* __restrict__ Bt,
                                        int m0, int n0, __bf16* smem,
                                        f32x4 acc[4][4]) {
  const int t = threadIdx.x, wv = t >> 6, lane = t & 63;
  const int g2 = lane >> 4, c = lane & 15;
  __bf16* At = smem;
  __bf16* Bs = smem + 4096;
  const int ch0 = wv * 64 + lane;
  const int ch1 = 256 + ch0;
  const __bf16* gA0 = A  + (size_t)(m0 + (ch0 >> 2)) * CDIM + ((ch0 & 3) << 3);
  const __bf16* gA1 = A  + (size_t)(m0 + (ch1 >> 2)) * CDIM + ((ch1 & 3) << 3);
  const __bf16* gB0 = Bt + (size_t)(n0 + (ch0 >> 2)) * CDIM + ((ch0 & 3) << 3);
  const __bf16* gB1 = Bt + (size_t)(n0 + (ch1 >> 2)) * CDIM + ((ch1 & 3) << 3);
  __bf16* lA0 = At + (size_t)(wv * 64) * 8;
  __bf16* lA1 = At + (size_t)(256 + wv * 64) * 8;
  __bf16* lB0 = Bs + (size_t)(wv * 64) * 8;
  __bf16* lB1 = Bs + (size_t)(256 + wv * 64) * 8;
  const int mw = (wv & 1) << 6, nw = (wv >> 1) << 6;

  for (int kk = 0; kk < CDIM / 32; ++kk) {
    __syncthreads();
    gl16(gA0, lA0); gl16(gA1, lA1);
    gl16(gB0, lB0); gl16(gB1, lB1);
    gA0 += 32; gA1 += 32; gB0 += 32; gB1 += 32;
    __syncthreads();
    bf16x8 af[4], bfr[4];
#pragma unroll
    for (int mq = 0; mq < 4; ++mq)
      af[mq] = *(const bf16x8*)&At[(size_t)(mw + mq * 16 + c) * 32 + (g2 << 3)];
#pragma unroll
    for (int nq = 0; nq < 4; ++nq)
      bfr[nq] = *(const bf16x8*)&Bs[(size_t)(nw + nq * 16 + c) * 32 + (g2 << 3)];
#pragma unroll
    for (int mq = 0; mq < 4; ++mq)
#pragma unroll
      for (int nq = 0; nq < 4; ++nq)
        acc[mq][nq] = __builtin_amdgcn_mfma_f32_16x16x32_bf16(
            af[mq], bfr[nq], acc[mq][nq], 0, 0, 0);
  }
  __syncthreads();
}

// ---------------------------------------------------------------------------
// Kernel 1: qkv projection (bf16 MFMA) + re-tile epilogue (R4-validated).
// R16-validated XCD-chunked block swizzle (T1): w = (l%8)*(nwg/8) + l/8.
// R19 (VGPR cap -> acc spill, 8.5% MfmaUtil) and R20 (persistent pairing,
// -50us: serializing tiles kills inter-block overlap) both REFUTED —
// this natural-register 1152-block form is the measured optimum.
// ---------------------------------------------------------------------------
__global__ __launch_bounds__(256) void qkv_mm_kernel(
    const __bf16* __restrict__ xb, const __bf16* __restrict__ Wt,
    const float* __restrict__ bias, __bf16* __restrict__ Qw,
    __bf16* __restrict__ Kw, __bf16* __restrict__ Vtw) {
  __shared__ __align__(16) __bf16 smem[18432];
  f32x4 acc[4][4];
#pragma unroll
  for (int i = 0; i < 4; ++i)
#pragma unroll
    for (int j = 0; j < 4; ++j) acc[i][j] = (f32x4){0.f, 0.f, 0.f, 0.f};

  const int nwg = (N3C / 128) * (MROWS / 128);   // 1152
  const int l   = (int)(blockIdx.x + gridDim.x * blockIdx.y);
  const int w   = (l & 7) * (nwg >> 3) + (l >> 3);
  const int m0  = (w / (N3C / 128)) * 128;
  const int n0  = (w % (N3C / 128)) * 128;
  mm_loop(xb, Wt, m0, n0, smem, acc);

  const int t = threadIdx.x, wv = t >> 6, lane = t & 63;
  const int g2 = lane >> 4, c = lane & 15;
  const int sel = n0 / CDIM;
  const int nn0 = n0 - sel * CDIM;
  const int h   = (nn0 >> 6) + (wv >> 1);
  const int mbase = m0 + ((wv & 1) << 6);
  const int b = mbase >> 12, tp0 = mbase & 4095;
  const int bh = b * NH + h;
  __bf16* Ep = smem + wv * 4608;
  float bcol[4];
#pragma unroll
  for (int nq = 0; nq < 4; ++nq)
    bcol[nq] = bias[n0 + ((wv >> 1) << 6) + nq * 16 + c];

  const int r8 = lane >> 3, c8 = (lane & 7) << 3;
  if (sel < 2) {
    const float scl = (sel == 0) ? QSCALE : 1.0f;
#pragma unroll
    for (int mq = 0; mq < 4; ++mq)
#pragma unroll
      for (int nq = 0; nq < 4; ++nq)
#pragma unroll
        for (int r = 0; r < 4; ++r)
          Ep[(size_t)(mq * 16 + (g2 << 2) + r) * 72 + nq * 16 + c] =
              (__bf16)((acc[mq][nq][r] + bcol[nq]) * scl);
    asm volatile("s_waitcnt lgkmcnt(0)" ::: "memory");
    __bf16* dst = (sel == 0) ? Qw : Kw;
#pragma unroll
    for (int p = 0; p < 8; ++p) {
      int row = p * 8 + r8;
      bf16x8 v = *(const bf16x8*)&Ep[(size_t)row * 72 + c8];
      *(bf16x8*)&dst[((size_t)bh * T_SEQ + tp0 + row) * HD + c8] = v;
    }
  } else {
#pragma unroll
    for (int mq = 0; mq < 4; ++mq)
#pragma unroll
      for (int nq = 0; nq < 4; ++nq)
#pragma unroll
        for (int r = 0; r < 4; ++r)
          Ep[(size_t)(nq * 16 + c) * 72 + mq * 16 + (g2 << 2) + r] =
              (__bf16)(acc[mq][nq][r] + bcol[nq]);
    asm volatile("s_waitcnt lgkmcnt(0)" ::: "memory");
#pragma unroll
    for (int p = 0; p < 8; ++p) {
      int d = p * 8 + r8;
      bf16x8 v = *(const bf16x8*)&Ep[(size_t)d * 72 + c8];
      *(bf16x8*)&Vtw[((size_t)bh * HD + d) * T_SEQ + tp0 + c8] = v;
    }
  }
}

// ---------------------------------------------------------------------------
// Kernel 2: causal flash attention. R10 VERBATIM — the experimentally
// established local optimum (~103.2us). Structural deviations refuted:
// R11 counted-vmcnt/triple-buf (+3.5), R12 ones-MFMA l (+1), R13 V-from-L2
// (+268), R14 128-thread sharing (+21.5), R15 K-from-L2 (+120),
// R17 setprio (+3). Keep: uniform sequential complement pairing
// (65 iters/block), double-buffered K+V gl16 staging w/ inverse-swizzled
// source, XOR-swizzled reads, fixed-shift base-2 softmax in the C-init,
// raw v_exp_f32, VALU l-accum + epilogue shuffles.
// ---------------------------------------------------------------------------
__device__ __forceinline__ void stage_tile(const __bf16* gk, const __bf16* gv,
                                           __bf16* ldsK, __bf16* ldsV) {
  gl16(gk,              ldsK);
  gl16(gk + 8 * HD,     ldsK + 8 * 64);
  gl16(gv,              ldsV);
  gl16(gv + 8 * T_SEQ,  ldsV + 8 * 64);
}

__device__ __forceinline__ void attn_tile(
    const __bf16* __restrict__ Qb, const __bf16* __restrict__ Kb,
    const __bf16* __restrict__ Vb, __bf16* __restrict__ O,
    int b, int hh, int qt, int wv, int lane, int g2, int c,
    __bf16 (*KT)[64][64], __bf16 (*VT)[64][64]) {
  const int qw = qt * 64 + wv * 16;   // wave owns 16 q rows

  // Q^T B-fragments (QK, K-dim = d): lane holds Q[qw+c][ds*32+8*g2..+7]
  bf16x8 qf0 = *(const bf16x8*)&Qb[(size_t)(qw + c) * HD +      (g2 << 3)];
  bf16x8 qf1 = *(const bf16x8*)&Qb[(size_t)(qw + c) * HD + 32 + (g2 << 3)];

  f32x4 ot[4];
#pragma unroll
  for (int dt = 0; dt < 4; ++dt) ot[dt] = (f32x4){0.f, 0.f, 0.f, 0.f};
  f32x4 lacc = (f32x4){0.f, 0.f, 0.f, 0.f};

  // per-lane global source for gl16 staging (inverse-swizzled column)
  const int rr = lane >> 3;
  const int lc = ((lane & 7) ^ rr) << 3;
  const __bf16* gk = Kb + (size_t)(wv * 16 + rr) * HD    + lc;
  const __bf16* gv = Vb + (size_t)(wv * 16 + rr) * T_SEQ + lc;

  stage_tile(gk, gv, &KT[0][wv * 16][0], &VT[0][wv * 16][0]);
  gk += 64 * HD; gv += 64;
  __syncthreads();

  const int swz  = (c & 7) << 3;
  const int qloc = (wv << 4) + c;
  const f32x4 SINIT = (f32x4){SSHIFT, SSHIFT, SSHIFT, SSHIFT};

#pragma unroll 1
  for (int kt = 0; kt <= qt; ++kt) {
    const int cur = kt & 1;
    if (kt < qt) {
      stage_tile(gk, gv, &KT[cur ^ 1][wv * 16][0], &VT[cur ^ 1][wv * 16][0]);
      gk += 64 * HD; gv += 64;
    }

    // S[s=64][q=16] = K . Q^T + SSHIFT (4 s-subtiles)
    f32x4 S[4];
#pragma unroll
    for (int st = 0; st < 4; ++st) {
      bf16x8 kfa = *(const bf16x8*)&KT[cur][st * 16 + c][(g2 << 3) ^ swz];
      bf16x8 kfb = *(const bf16x8*)&KT[cur][st * 16 + c][((4 + g2) << 3) ^ swz];
      S[st] = __builtin_amdgcn_mfma_f32_16x16x32_bf16(kfa, qf0, SINIT, 0, 0, 0);
      S[st] = __builtin_amdgcn_mfma_f32_16x16x32_bf16(kfb, qf1, S[st], 0, 0, 0);
    }

    if (kt == qt) {   // diagonal tile
#pragma unroll
      for (int st = 0; st < 4; ++st)
#pragma unroll
        for (int r = 0; r < 4; ++r)
          if ((st << 4) + (g2 << 2) + r > qloc) S[st][r] = -INFINITY;
    }

    // P = 2^S in-register (raw v_exp_f32)
    s16x4 pf[4];
#pragma unroll
    for (int st = 0; st < 4; ++st) {
      bf16x4 ph;
#pragma unroll
      for (int r = 0; r < 4; ++r) {
        float pl = __builtin_amdgcn_exp2f(S[st][r]);
        lacc[r] += pl;
        ph[r] = (__bf16)pl;
      }
      pf[st] = as_s16(ph);
    }

    // O += V^T . P : 4 dt x 4 st of 16x16x16
#pragma unroll
    for (int dt = 0; dt < 4; ++dt) {
#pragma unroll
      for (int st = 0; st < 4; ++st) {
        bf16x4 vh = *(const bf16x4*)&VT[cur][dt * 16 + c]
                                       [((st << 4) + (g2 << 2)) ^ swz];
        ot[dt] = __builtin_amdgcn_mfma_f32_16x16x16bf16_1k(as_s16(vh), pf[st],
                                                           ot[dt], 0, 0, 0);
      }
    }
    __syncthreads();
  }

  // ---- epilogue: finish l, normalize, write bf16 O ----
  float l = lacc[0] + lacc[1] + lacc[2] + lacc[3];
  l += __shfl_xor(l, 16);
  l += __shfl_xor(l, 32);
  const float inv = 1.f / l;
  __bf16* orow = O + ((size_t)(b * T_SEQ + qw + c)) * CDIM + hh * HD;
#pragma unroll
  for (int dt = 0; dt < 4; ++dt) {
    bf16x4 v;
    v[0] = (__bf16)(ot[dt][0] * inv); v[1] = (__bf16)(ot[dt][1] * inv);
    v[2] = (__bf16)(ot[dt][2] * inv); v[3] = (__bf16)(ot[dt][3] * inv);
    *(bf16x4*)&orow[dt * 16 + (g2 << 2)] = v;
  }
}

__global__ __launch_bounds__(256) void attn_kernel(
    const __bf16* __restrict__ Q, const __bf16* __restrict__ K,
    const __bf16* __restrict__ Vt, __bf16* __restrict__ O) {
  __shared__ __align__(16) __bf16 KT[2][64][64];   // 16 KB, XOR-swizzled
  __shared__ __align__(16) __bf16 VT[2][64][64];   // 16 KB, XOR-swizzled

  const int t    = threadIdx.x;
  const int wv   = t >> 6;
  const int lane = t & 63;
  const int g2   = lane >> 4;
  const int c    = lane & 15;
  const int bh   = blockIdx.x;              // XCD-local (24 ≡ 0 mod 8)
  const int p    = (int)blockIdx.y;         // 0..31

  const __bf16* Qb = Q  + (size_t)bh * T_SEQ * HD;
  const __bf16* Kb = K  + (size_t)bh * T_SEQ * HD;
  const __bf16* Vb = Vt + (size_t)bh * HD * T_SEQ;
  const int b = bh / NH, hh = bh % NH;

  // Phase A: q-tile p (k = 0..p). Phase B: q-tile 63-p (k = 0..63-p).
  // Total = 65 k-iterations for every block: exactly uniform cost.
  attn_tile(Qb, Kb, Vb, O, b, hh, p,      wv, lane, g2, c, KT, VT);
  attn_tile(Qb, Kb, Vb, O, b, hh, 63 - p, wv, lane, g2, c, KT, VT);
}

// ---------------------------------------------------------------------------
// Kernel 3: out = Ob @ Wprojt^T + b_proj (bf16 MFMA, fp32 out).
// R16-validated XCD-chunked swizzle (nwg = 384). Grid is 1.5 blocks/CU —
// already fully resident at natural VGPR.
// ---------------------------------------------------------------------------
__global__ __launch_bounds__(256) void proj_mm_kernel(
    const __bf16* __restrict__ Ob, const __bf16* __restrict__ Wt,
    const float* __restrict__ bias, float* __restrict__ out) {
  __shared__ __align__(16) __bf16 smem[8192];
  f32x4 acc[4][4];
#pragma unroll
  for (int i = 0; i < 4; ++i)
#pragma unroll
    for (int j = 0; j < 4; ++j) acc[i][j] = (f32x4){0.f, 0.f, 0.f, 0.f};

  const int nwg = (CDIM / 128) * (MROWS / 128);   // 384
  const int l   = (int)(blockIdx.x + gridDim.x * blockIdx.y);
  const int w   = (l & 7) * (nwg >> 3) + (l >> 3);
  const int m0  = (w / (CDIM / 128)) * 128;
  const int n0  = (w % (CDIM / 128)) * 128;
  mm_loop(Ob, Wt, m0, n0, smem, acc);

  const int t = threadIdx.x, wv = t >> 6, lane = t & 63;
  const int g2 = lane >> 4, c = lane & 15;
  const int mb = m0 + ((wv & 1) << 6), nb = n0 + ((wv >> 1) << 6);
  float bcol[4];
#pragma unroll
  for (int nq = 0; nq < 4; ++nq) bcol[nq] = bias[nb + nq * 16 + c];
#pragma unroll
  for (int mq = 0; mq < 4; ++mq)
#pragma unroll
    for (int nq = 0; nq < 4; ++nq)
#pragma unroll
      for (int r = 0; r < 4; ++r)
        out[(size_t)(mb + mq * 16 + (g2 << 2) + r) * CDIM + nb + nq * 16 + c] =
            acc[mq][nq][r] + bcol[nq];
}

// ---------------------------------------------------------------------------
extern "C" void kernel_launch(void* const* d_in, const int* in_sizes, int n_in,
                              void* d_out, int out_size, void* d_ws, size_t ws_size,
                              hipStream_t stream) {
  (void)in_sizes; (void)n_in; (void)out_size; (void)ws_size;
  const float* x      = (const float*)d_in[0];
  const float* W_qkv  = (const float*)d_in[1];
  const float* b_qkv  = (const float*)d_in[2];
  const float* W_proj = (const float*)d_in[3];
  const float* b_proj = (const float*)d_in[4];
  float* out = (float*)d_out;

  __bf16* Qw     = (__bf16*)d_ws;
  __bf16* Kw     = Qw  + QKV_ELEMS;
  __bf16* Vtw    = Kw  + QKV_ELEMS;
  __bf16* Ob     = Vtw + QKV_ELEMS;
  __bf16* xb     = Ob  + QKV_ELEMS;
  __bf16* Wqkvt  = xb  + QKV_ELEMS;
  __bf16* Wprojt = Wqkvt + (size_t)CDIM * N3C;

  // Fused preps: 3072 cast blocks + 432 W_qkv tcast + 144 W_proj tcast
  prep_kernel<<<3072 + 432 + 144, 256, 0, stream>>>(
      x, xb, W_qkv, Wqkvt, W_proj, Wprojt);

  qkv_mm_kernel<<<dim3(N3C / 128, MROWS / 128), 256, 0, stream>>>(
      xb, Wqkvt, b_qkv, Qw, Kw, Vtw);

  attn_kernel<<<dim3(HEADS_TOTAL, 32), 256, 0, stream>>>(Qw, Kw, Vtw, Ob);

  proj_mm_kernel<<<dim3(CDIM / 128, MROWS / 128), 256, 0, stream>>>(
      Ob, Wprojt, b_proj, out);
}